// Round 11
// baseline (440.682 us; speedup 1.0000x reference)
//
#include <hip/hip_runtime.h>

#define CC 192
#define WFRAG_USHORTS (4*6*12*512)
#define SX 202   // [tok][ch] stride (ushorts): 404B = 101 dwords == 5 mod 32

typedef __attribute__((ext_vector_type(8))) short bf16x8;
typedef __attribute__((ext_vector_type(4))) float f32x4;

__device__ __forceinline__ unsigned short f2b(float f){
  unsigned u = __float_as_uint(f);
  return (unsigned short)((u + 0x7fffu + ((u >> 16) & 1u)) >> 16);
}
__device__ __forceinline__ unsigned pk2(float a, float b){
  return (unsigned)f2b(a) | ((unsigned)f2b(b) << 16);
}

// Weights packed in MFMA-fragment order: Wf[mat][k][n][lane][8]; one wave
// B/A-fragment = one contiguous 1KB block. 1/sqrt(32) folded into Q mat+bias.
__global__ void fuse_weights(const float* __restrict__ wq, const float* __restrict__ bq,
                             const float* __restrict__ wk, const float* __restrict__ bk,
                             const float* __restrict__ wv, const float* __restrict__ bv,
                             const float* __restrict__ in_w, const float* __restrict__ in_b,
                             const float* __restrict__ out_w, const float* __restrict__ out_b,
                             const float* __restrict__ proj_w, const float* __restrict__ proj_b,
                             unsigned short* __restrict__ Wf, float* __restrict__ Bf)
{
  int mat = blockIdx.x / CC, o = blockIdx.x % CC, ci = threadIdx.x;
  const float *A, *Bm, *bs, *ba; int aoff, boff; float scale = 1.f;
  if (mat == 0){ A=in_w; aoff=0;    Bm=wq;    bs=bq;    ba=in_b;   boff=0;    scale=0.17677669529663687f; }
  else if (mat==1){ A=in_w; aoff=CC;   Bm=wk;    bs=bk;    ba=in_b;   boff=CC;   }
  else if (mat==2){ A=in_w; aoff=2*CC; Bm=wv;    bs=bv;    ba=in_b;   boff=2*CC; }
  else            { A=proj_w; aoff=0;  Bm=out_w; bs=out_b; ba=proj_b; boff=0;    }
  const float* ar = A + (size_t)(aoff + o) * CC;
  float acc = 0.f;
  for (int m = 0; m < CC; ++m) acc = fmaf(ar[m], Bm[m*CC + ci], acc);
  int k = ci >> 5, n = o >> 4, lgv = (ci >> 3) & 3, e = ci & 7;
  int lane = (o & 15) | (lgv << 4);
  Wf[(((mat*6 + k)*12 + n) << 9) + lane*8 + e] = f2b(acc * scale);
  if (ci == 0){
    float bacc = 0.f;
    for (int m = 0; m < CC; ++m) bacc = fmaf(ar[m], bs[m], bacc);
    Bf[mat*CC + o] = (bacc + ba[boff + o]) * scale;
  }
}

__global__ __launch_bounds__(384, 3) void win_attn(
    const float* __restrict__ q2d, const float* __restrict__ kv2d,
    const unsigned short* __restrict__ Wf, const float* __restrict__ Bf,
    float* __restrict__ out)
{
  __shared__ unsigned short QK[2][64*SX]; // [0]: Xq -> Q -> O ; [1]: Xkv -> K

  const int t = threadIdx.x;
  const int w = t >> 6, lane = t & 63, lr = lane & 15, lg = lane >> 4;
  const int bid = blockIdx.x;
  const int wid = (bid & 7) * 512 + (bid >> 3);   // XCD-chunked, bijective
  const int b = wid >> 10, l = wid & 1023;
  const int y0 = (l >> 5) << 3, x0 = (l & 31) << 3;
  const float* qsrc  = q2d  + (size_t)b * CC * 65536;
  const float* kvsrc = kv2d + (size_t)b * CC * 65536;
  const int tb2 = 2 * w;     // wave's 2 16-ch tiles == head w's 32 channels

  auto stage = [&](const float* __restrict__ src, unsigned short* __restrict__ dst){
    #pragma unroll
    for (int i = 0; i < 4; ++i){
      int lin = i*384 + t;
      int c2 = lin >> 4, tok0 = (lin & 15) << 2;
      int gy = (y0 + (tok0 >> 3)) * 256 + x0 + (tok0 & 7);
      float4 va = *(const float4*)&src[(size_t)(2*c2)   * 65536 + gy];
      float4 vb = *(const float4*)&src[(size_t)(2*c2+1) * 65536 + gy];
      float fa[4] = {va.x, va.y, va.z, va.w};
      float fb[4] = {vb.x, vb.y, vb.z, vb.w};
      #pragma unroll
      for (int jj = 0; jj < 4; ++jj)
        *(unsigned*)&dst[(tok0 + jj)*SX + 2*c2] = pk2(fa[jj], fb[jj]);
    }
  };

  // ---- preload V + Q weight fragments; latency hides under X staging ----
  bf16x8 vw[2][6], qw[2][6];
  #pragma unroll
  for (int i = 0; i < 2; ++i)
    #pragma unroll
    for (int k = 0; k < 6; ++k){
      vw[i][k] = *(const bf16x8*)&Wf[(((12 + k)*12 + tb2 + i) << 9) + lane*8];
      qw[i][k] = *(const bf16x8*)&Wf[((( 0 + k)*12 + tb2 + i) << 9) + lane*8];
    }
  __builtin_amdgcn_sched_barrier(0);

  stage(qsrc,  QK[0]);
  stage(kvsrc, QK[1]);
  __syncthreads();                                    // B1

  // ---- A1: V projection (head w's 32 chs) from vw regs ----
  bf16x8 vp[2][2];
  {
    f32x4 vacc[2][4] = {};
    #pragma unroll
    for (int k = 0; k < 6; ++k){
      bf16x8 a[4];
      #pragma unroll
      for (int m = 0; m < 4; ++m)
        a[m] = *(const bf16x8*)&QK[1][(m*16 + lr)*SX + k*32 + lg*8];
      #pragma unroll
      for (int i = 0; i < 2; ++i)
        #pragma unroll
        for (int m = 0; m < 4; ++m)
          vacc[i][m] = __builtin_amdgcn_mfma_f32_16x16x32_bf16(a[m], vw[i][k], vacc[i][m], 0, 0, 0);
    }
    #pragma unroll
    for (int i = 0; i < 2; ++i){
      float bb = Bf[2*CC + (tb2 + i)*16 + lr];
      #pragma unroll
      for (int kt = 0; kt < 2; ++kt){
        bf16x8 v;
        ((unsigned*)&v)[0] = pk2(vacc[i][2*kt][0] + bb,   vacc[i][2*kt][1] + bb);
        ((unsigned*)&v)[1] = pk2(vacc[i][2*kt][2] + bb,   vacc[i][2*kt][3] + bb);
        ((unsigned*)&v)[2] = pk2(vacc[i][2*kt+1][0] + bb, vacc[i][2*kt+1][1] + bb);
        ((unsigned*)&v)[3] = pk2(vacc[i][2*kt+1][2] + bb, vacc[i][2*kt+1][3] + bb);
        vp[i][kt] = v;
      }
    }
  }

  // ---- preload K weights (vw dead; latency hides under Q projection) ----
  bf16x8 kw[2][6];
  #pragma unroll
  for (int i = 0; i < 2; ++i)
    #pragma unroll
    for (int k = 0; k < 6; ++k)
      kw[i][k] = *(const bf16x8*)&Wf[(((6 + k)*12 + tb2 + i) << 9) + lane*8];
  __builtin_amdgcn_sched_barrier(0);

  // ---- A2: Q projection (reads QK[0]=Xq) from qw regs ----
  {
    f32x4 qacc[2][4] = {};
    #pragma unroll
    for (int k = 0; k < 6; ++k){
      bf16x8 a[4];
      #pragma unroll
      for (int m = 0; m < 4; ++m)
        a[m] = *(const bf16x8*)&QK[0][(m*16 + lr)*SX + k*32 + lg*8];
      #pragma unroll
      for (int i = 0; i < 2; ++i)
        #pragma unroll
        for (int m = 0; m < 4; ++m)
          qacc[i][m] = __builtin_amdgcn_mfma_f32_16x16x32_bf16(a[m], qw[i][k], qacc[i][m], 0, 0, 0);
    }
    __syncthreads();                                  // B2: all Xq reads done
    #pragma unroll
    for (int i = 0; i < 2; ++i){
      int ch = (tb2 + i)*16 + lr;
      float bb = Bf[0*CC + ch];
      #pragma unroll
      for (int m = 0; m < 4; ++m)
        #pragma unroll
        for (int rr = 0; rr < 4; ++rr)
          QK[0][(m*16 + lg*4 + rr)*SX + ch] = f2b(qacc[i][m][rr] + bb);
    }
  }

  // ---- A3: K projection (reads QK[1]=Xkv) from kw regs ----
  bf16x8 ow[2][6];
  {
    f32x4 kacc[2][4] = {};
    #pragma unroll
    for (int k = 0; k < 6; ++k){
      bf16x8 a[4];
      #pragma unroll
      for (int m = 0; m < 4; ++m)
        a[m] = *(const bf16x8*)&QK[1][(m*16 + lr)*SX + k*32 + lg*8];
      #pragma unroll
      for (int i = 0; i < 2; ++i)
        #pragma unroll
        for (int m = 0; m < 4; ++m)
          kacc[i][m] = __builtin_amdgcn_mfma_f32_16x16x32_bf16(a[m], kw[i][k], kacc[i][m], 0, 0, 0);
    }
    // preload out-proj weights (kw dead; hides under writeback+barriers+attn)
    #pragma unroll
    for (int i = 0; i < 2; ++i)
      #pragma unroll
      for (int k = 0; k < 6; ++k)
        ow[i][k] = *(const bf16x8*)&Wf[(((18 + k)*12 + tb2 + i) << 9) + lane*8];
    __builtin_amdgcn_sched_barrier(0);
    __syncthreads();                                  // B3: all Xkv reads done
    #pragma unroll
    for (int i = 0; i < 2; ++i){
      int ch = (tb2 + i)*16 + lr;
      float bb = Bf[1*CC + ch];
      #pragma unroll
      for (int m = 0; m < 4; ++m)
        #pragma unroll
        for (int rr = 0; rr < 4; ++rr)
          QK[1][(m*16 + lg*4 + rr)*SX + ch] = f2b(kacc[i][m][rr] + bb);
    }
  }
  __syncthreads();                                    // B4: Q and K visible

  // ---- attention: wave w == head w; V in regs; K frags hoisted ----
  {
    const int h = w;
    bf16x8 ka[4];
    #pragma unroll
    for (int m = 0; m < 4; ++m)
      ka[m] = *(const bf16x8*)&QK[1][(m*16 + lr)*SX + h*32 + lg*8];
    #pragma unroll
    for (int r = 0; r < 4; ++r){
      const int r0 = r << 4;
      f32x4 st[4] = {};
      bf16x8 bq_ = *(const bf16x8*)&QK[0][(r0 + lr)*SX + h*32 + lg*8];
      #pragma unroll
      for (int m = 0; m < 4; ++m)
        st[m] = __builtin_amdgcn_mfma_f32_16x16x32_bf16(ka[m], bq_, st[m], 0, 0, 0);
      float mx = st[0][0];
      #pragma unroll
      for (int m = 0; m < 4; ++m)
        #pragma unroll
        for (int rr = 0; rr < 4; ++rr) mx = fmaxf(mx, st[m][rr]);
      mx = fmaxf(mx, __shfl_xor(mx, 16));
      mx = fmaxf(mx, __shfl_xor(mx, 32));
      float p[16]; float s = 0.f;
      #pragma unroll
      for (int m = 0; m < 4; ++m)
        #pragma unroll
        for (int rr = 0; rr < 4; ++rr){ float e = __expf(st[m][rr] - mx); p[m*4+rr] = e; s += e; }
      s += __shfl_xor(s, 16); s += __shfl_xor(s, 32);
      float inv = 1.f / s;
      #pragma unroll
      for (int i2 = 0; i2 < 16; ++i2) p[i2] *= inv;
      f32x4 o0 = {}, o1 = {};
      #pragma unroll
      for (int kt = 0; kt < 2; ++kt){
        bf16x8 ap;
        ((unsigned*)&ap)[0] = pk2(p[8*kt+0], p[8*kt+1]);
        ((unsigned*)&ap)[1] = pk2(p[8*kt+2], p[8*kt+3]);
        ((unsigned*)&ap)[2] = pk2(p[8*kt+4], p[8*kt+5]);
        ((unsigned*)&ap)[3] = pk2(p[8*kt+6], p[8*kt+7]);
        o0 = __builtin_amdgcn_mfma_f32_16x16x32_bf16(ap, vp[0][kt], o0, 0, 0, 0);
        o1 = __builtin_amdgcn_mfma_f32_16x16x32_bf16(ap, vp[1][kt], o1, 0, 0, 0);
      }
      // O overwrites this head's own Q cells (read bq_ above, sole reader)
      #pragma unroll
      for (int rr = 0; rr < 4; ++rr){
        int tok = r0 + lg*4 + rr;
        QK[0][tok*SX + h*32 + lr]      = f2b(o0[rr]);
        QK[0][tok*SX + h*32 + 16 + lr] = f2b(o1[rr]);
      }
    }
  }
  __syncthreads();                                    // B5: O complete

  // ---- out-proj: E2^T = Wo_f * O^T from ow regs ----
  {
    f32x4 eo[2][4] = {};
    #pragma unroll
    for (int k = 0; k < 6; ++k){
      bf16x8 bo[4];
      #pragma unroll
      for (int nt = 0; nt < 4; ++nt)
        bo[nt] = *(const bf16x8*)&QK[0][(nt*16 + lr)*SX + k*32 + lg*8];
      #pragma unroll
      for (int i = 0; i < 2; ++i)
        #pragma unroll
        for (int nt = 0; nt < 4; ++nt)
          eo[i][nt] = __builtin_amdgcn_mfma_f32_16x16x32_bf16(ow[i][k], bo[nt], eo[i][nt], 0, 0, 0);
    }
    #pragma unroll
    for (int i = 0; i < 2; ++i){
      #pragma unroll
      for (int rr = 0; rr < 4; ++rr){
        int o = (tb2 + i)*16 + lg*4 + rr;
        float bb = Bf[3*CC + o];
        #pragma unroll
        for (int nt = 0; nt < 4; ++nt){
          int tok = nt*16 + lr;
          size_t g = (size_t)(b*CC + o)*65536 + (size_t)(y0 + (tok >> 3))*256 + x0 + (tok & 7);
          out[g] = eo[i][nt][rr] + bb + q2d[g];
        }
      }
    }
  }
}

extern "C" void kernel_launch(void* const* d_in, const int* in_sizes, int n_in,
                              void* d_out, int out_size, void* d_ws, size_t ws_size,
                              hipStream_t stream)
{
  const float* q2d    = (const float*)d_in[0];
  const float* kv2d   = (const float*)d_in[1];
  const float* wq     = (const float*)d_in[2];
  const float* bq     = (const float*)d_in[3];
  const float* wk     = (const float*)d_in[4];
  const float* bk     = (const float*)d_in[5];
  const float* wv     = (const float*)d_in[6];
  const float* bv     = (const float*)d_in[7];
  const float* in_w   = (const float*)d_in[8];
  const float* in_b   = (const float*)d_in[9];
  const float* out_w  = (const float*)d_in[10];
  const float* out_b  = (const float*)d_in[11];
  const float* proj_w = (const float*)d_in[12];
  const float* proj_b = (const float*)d_in[13];

  unsigned short* Wf = (unsigned short*)d_ws;
  float* Bf = (float*)((char*)d_ws + WFRAG_USHORTS*2);
  float* out = (float*)d_out;

  fuse_weights<<<4*CC, CC, 0, stream>>>(wq,bq,wk,bk,wv,bv,in_w,in_b,
                                        out_w,out_b,proj_w,proj_b, Wf, Bf);
  win_attn<<<4096, 384, 0, stream>>>(q2d, kv2d, Wf, Bf, out);
}

// Round 12
// 363.439 us; speedup vs baseline: 1.2125x; 1.2125x over previous
//
#include <hip/hip_runtime.h>

#define CC 192
#define WFRAG_USHORTS (4*6*12*512)
#define SX 202   // [tok][ch] stride (ushorts): 404B = 101 dwords == 5 mod 32

typedef __attribute__((ext_vector_type(8))) short bf16x8;
typedef __attribute__((ext_vector_type(4))) float f32x4;

__device__ __forceinline__ unsigned short f2b(float f){
  unsigned u = __float_as_uint(f);
  return (unsigned short)((u + 0x7fffu + ((u >> 16) & 1u)) >> 16);
}
__device__ __forceinline__ unsigned pk2(float a, float b){
  return (unsigned)f2b(a) | ((unsigned)f2b(b) << 16);
}

// Weights packed in MFMA-fragment order: Wf[mat][k][n][lane][8]; one wave
// B/A-fragment = one contiguous 1KB block. 1/sqrt(32) folded into Q mat+bias.
__global__ void fuse_weights(const float* __restrict__ wq, const float* __restrict__ bq,
                             const float* __restrict__ wk, const float* __restrict__ bk,
                             const float* __restrict__ wv, const float* __restrict__ bv,
                             const float* __restrict__ in_w, const float* __restrict__ in_b,
                             const float* __restrict__ out_w, const float* __restrict__ out_b,
                             const float* __restrict__ proj_w, const float* __restrict__ proj_b,
                             unsigned short* __restrict__ Wf, float* __restrict__ Bf)
{
  int mat = blockIdx.x / CC, o = blockIdx.x % CC, ci = threadIdx.x;
  const float *A, *Bm, *bs, *ba; int aoff, boff; float scale = 1.f;
  if (mat == 0){ A=in_w; aoff=0;    Bm=wq;    bs=bq;    ba=in_b;   boff=0;    scale=0.17677669529663687f; }
  else if (mat==1){ A=in_w; aoff=CC;   Bm=wk;    bs=bk;    ba=in_b;   boff=CC;   }
  else if (mat==2){ A=in_w; aoff=2*CC; Bm=wv;    bs=bv;    ba=in_b;   boff=2*CC; }
  else            { A=proj_w; aoff=0;  Bm=out_w; bs=out_b; ba=proj_b; boff=0;    }
  const float* ar = A + (size_t)(aoff + o) * CC;
  float acc = 0.f;
  for (int m = 0; m < CC; ++m) acc = fmaf(ar[m], Bm[m*CC + ci], acc);
  int k = ci >> 5, n = o >> 4, lgv = (ci >> 3) & 3, e = ci & 7;
  int lane = (o & 15) | (lgv << 4);
  Wf[(((mat*6 + k)*12 + n) << 9) + lane*8 + e] = f2b(acc * scale);
  if (ci == 0){
    float bacc = 0.f;
    for (int m = 0; m < CC; ++m) bacc = fmaf(ar[m], bs[m], bacc);
    Bf[mat*CC + o] = (bacc + ba[boff + o]) * scale;
  }
}

__global__ __launch_bounds__(384, 3) void win_attn(
    const float* __restrict__ q2d, const float* __restrict__ kv2d,
    const unsigned short* __restrict__ Wf, const float* __restrict__ Bf,
    float* __restrict__ out)
{
  __shared__ unsigned short QK[2][64*SX]; // [0]: Xq -> Q -> O ; [1]: Xkv -> K

  const int t = threadIdx.x;
  const int w = t >> 6, lane = t & 63, lr = lane & 15, lg = lane >> 4;
  const int bid = blockIdx.x;
  const int wid = (bid & 7) * 512 + (bid >> 3);   // XCD-chunked, bijective
  const int b = wid >> 10, l = wid & 1023;
  const int y0 = (l >> 5) << 3, x0 = (l & 31) << 3;
  const float* qsrc  = q2d  + (size_t)b * CC * 65536;
  const float* kvsrc = kv2d + (size_t)b * CC * 65536;
  const int tb2 = 2 * w;     // wave's 2 16-ch tiles == head w's 32 channels

  auto stage = [&](const float* __restrict__ src, unsigned short* __restrict__ dst){
    #pragma unroll
    for (int i = 0; i < 4; ++i){
      int lin = i*384 + t;
      int c2 = lin >> 4, tok0 = (lin & 15) << 2;
      int gy = (y0 + (tok0 >> 3)) * 256 + x0 + (tok0 & 7);
      float4 va = *(const float4*)&src[(size_t)(2*c2)   * 65536 + gy];
      float4 vb = *(const float4*)&src[(size_t)(2*c2+1) * 65536 + gy];
      float fa[4] = {va.x, va.y, va.z, va.w};
      float fb[4] = {vb.x, vb.y, vb.z, vb.w};
      #pragma unroll
      for (int jj = 0; jj < 4; ++jj)
        *(unsigned*)&dst[(tok0 + jj)*SX + 2*c2] = pk2(fa[jj], fb[jj]);
    }
  };

  // batched within-phase weight fetch: 12 frags, all in flight at once,
  // pinned at the issue point; consumed with static indices only.
  auto wbatch = [&](int mat, bf16x8 (&wf)[12]){
    #pragma unroll
    for (int i = 0; i < 2; ++i)
      #pragma unroll
      for (int k = 0; k < 6; ++k)
        wf[i*6 + k] = *(const bf16x8*)&Wf[(((mat*6 + k)*12 + tb2 + i) << 9) + lane*8];
    __builtin_amdgcn_sched_barrier(0);
  };

  stage(qsrc,  QK[0]);
  stage(kvsrc, QK[1]);
  __syncthreads();                                    // B1

  // ---- A1: V projection (head w's 32 chs), result stays in registers ----
  bf16x8 vp[2][2];
  {
    bf16x8 wf[12];
    wbatch(2, wf);
    f32x4 vacc[2][4] = {};
    #pragma unroll
    for (int k = 0; k < 6; ++k){
      bf16x8 a[4];
      #pragma unroll
      for (int m = 0; m < 4; ++m)
        a[m] = *(const bf16x8*)&QK[1][(m*16 + lr)*SX + k*32 + lg*8];
      #pragma unroll
      for (int i = 0; i < 2; ++i)
        #pragma unroll
        for (int m = 0; m < 4; ++m)
          vacc[i][m] = __builtin_amdgcn_mfma_f32_16x16x32_bf16(a[m], wf[i*6+k], vacc[i][m], 0, 0, 0);
    }
    #pragma unroll
    for (int i = 0; i < 2; ++i){
      float bb = Bf[2*CC + (tb2 + i)*16 + lr];
      #pragma unroll
      for (int kt = 0; kt < 2; ++kt){
        bf16x8 v;
        ((unsigned*)&v)[0] = pk2(vacc[i][2*kt][0] + bb,   vacc[i][2*kt][1] + bb);
        ((unsigned*)&v)[1] = pk2(vacc[i][2*kt][2] + bb,   vacc[i][2*kt][3] + bb);
        ((unsigned*)&v)[2] = pk2(vacc[i][2*kt+1][0] + bb, vacc[i][2*kt+1][1] + bb);
        ((unsigned*)&v)[3] = pk2(vacc[i][2*kt+1][2] + bb, vacc[i][2*kt+1][3] + bb);
        vp[i][kt] = v;
      }
    }
  }

  // ---- A2: Q projection (reads QK[0]=Xq) ----
  {
    bf16x8 wf[12];
    wbatch(0, wf);
    f32x4 qacc[2][4] = {};
    #pragma unroll
    for (int k = 0; k < 6; ++k){
      bf16x8 a[4];
      #pragma unroll
      for (int m = 0; m < 4; ++m)
        a[m] = *(const bf16x8*)&QK[0][(m*16 + lr)*SX + k*32 + lg*8];
      #pragma unroll
      for (int i = 0; i < 2; ++i)
        #pragma unroll
        for (int m = 0; m < 4; ++m)
          qacc[i][m] = __builtin_amdgcn_mfma_f32_16x16x32_bf16(a[m], wf[i*6+k], qacc[i][m], 0, 0, 0);
    }
    __syncthreads();                                  // B2: all Xq reads done
    #pragma unroll
    for (int i = 0; i < 2; ++i){
      int ch = (tb2 + i)*16 + lr;
      float bb = Bf[0*CC + ch];
      #pragma unroll
      for (int m = 0; m < 4; ++m)
        #pragma unroll
        for (int rr = 0; rr < 4; ++rr)
          QK[0][(m*16 + lg*4 + rr)*SX + ch] = f2b(qacc[i][m][rr] + bb);
    }
  }

  // ---- A3: K projection (reads QK[1]=Xkv) ----
  {
    bf16x8 wf[12];
    wbatch(1, wf);
    f32x4 kacc[2][4] = {};
    #pragma unroll
    for (int k = 0; k < 6; ++k){
      bf16x8 a[4];
      #pragma unroll
      for (int m = 0; m < 4; ++m)
        a[m] = *(const bf16x8*)&QK[1][(m*16 + lr)*SX + k*32 + lg*8];
      #pragma unroll
      for (int i = 0; i < 2; ++i)
        #pragma unroll
        for (int m = 0; m < 4; ++m)
          kacc[i][m] = __builtin_amdgcn_mfma_f32_16x16x32_bf16(a[m], wf[i*6+k], kacc[i][m], 0, 0, 0);
    }
    __syncthreads();                                  // B3: all Xkv reads done
    #pragma unroll
    for (int i = 0; i < 2; ++i){
      int ch = (tb2 + i)*16 + lr;
      float bb = Bf[1*CC + ch];
      #pragma unroll
      for (int m = 0; m < 4; ++m)
        #pragma unroll
        for (int rr = 0; rr < 4; ++rr)
          QK[1][(m*16 + lg*4 + rr)*SX + ch] = f2b(kacc[i][m][rr] + bb);
    }
  }
  __syncthreads();                                    // B4: Q and K visible

  // ---- attention: wave w == head w; V in regs; K frags hoisted ----
  {
    const int h = w;
    bf16x8 ka[4];
    #pragma unroll
    for (int m = 0; m < 4; ++m)
      ka[m] = *(const bf16x8*)&QK[1][(m*16 + lr)*SX + h*32 + lg*8];
    #pragma unroll
    for (int r = 0; r < 4; ++r){
      const int r0 = r << 4;
      f32x4 st[4] = {};
      bf16x8 bq_ = *(const bf16x8*)&QK[0][(r0 + lr)*SX + h*32 + lg*8];
      #pragma unroll
      for (int m = 0; m < 4; ++m)
        st[m] = __builtin_amdgcn_mfma_f32_16x16x32_bf16(ka[m], bq_, st[m], 0, 0, 0);
      float mx = st[0][0];
      #pragma unroll
      for (int m = 0; m < 4; ++m)
        #pragma unroll
        for (int rr = 0; rr < 4; ++rr) mx = fmaxf(mx, st[m][rr]);
      mx = fmaxf(mx, __shfl_xor(mx, 16));
      mx = fmaxf(mx, __shfl_xor(mx, 32));
      float p[16]; float s = 0.f;
      #pragma unroll
      for (int m = 0; m < 4; ++m)
        #pragma unroll
        for (int rr = 0; rr < 4; ++rr){ float e = __expf(st[m][rr] - mx); p[m*4+rr] = e; s += e; }
      s += __shfl_xor(s, 16); s += __shfl_xor(s, 32);
      float inv = 1.f / s;
      #pragma unroll
      for (int i2 = 0; i2 < 16; ++i2) p[i2] *= inv;
      f32x4 o0 = {}, o1 = {};
      #pragma unroll
      for (int kt = 0; kt < 2; ++kt){
        bf16x8 ap;
        ((unsigned*)&ap)[0] = pk2(p[8*kt+0], p[8*kt+1]);
        ((unsigned*)&ap)[1] = pk2(p[8*kt+2], p[8*kt+3]);
        ((unsigned*)&ap)[2] = pk2(p[8*kt+4], p[8*kt+5]);
        ((unsigned*)&ap)[3] = pk2(p[8*kt+6], p[8*kt+7]);
        o0 = __builtin_amdgcn_mfma_f32_16x16x32_bf16(ap, vp[0][kt], o0, 0, 0, 0);
        o1 = __builtin_amdgcn_mfma_f32_16x16x32_bf16(ap, vp[1][kt], o1, 0, 0, 0);
      }
      // O overwrites this head's own Q cells (read bq_ above, sole reader)
      #pragma unroll
      for (int rr = 0; rr < 4; ++rr){
        int tok = r0 + lg*4 + rr;
        QK[0][tok*SX + h*32 + lr]      = f2b(o0[rr]);
        QK[0][tok*SX + h*32 + 16 + lr] = f2b(o1[rr]);
      }
    }
  }
  __syncthreads();                                    // B5: O complete

  // ---- out-proj: E2^T = Wo_f * O^T; wave w owns out tiles tb2, tb2+1 ----
  {
    bf16x8 wf[12];
    wbatch(3, wf);
    f32x4 eo[2][4] = {};
    #pragma unroll
    for (int k = 0; k < 6; ++k){
      bf16x8 bo[4];
      #pragma unroll
      for (int nt = 0; nt < 4; ++nt)
        bo[nt] = *(const bf16x8*)&QK[0][(nt*16 + lr)*SX + k*32 + lg*8];
      #pragma unroll
      for (int i = 0; i < 2; ++i)
        #pragma unroll
        for (int nt = 0; nt < 4; ++nt)
          eo[i][nt] = __builtin_amdgcn_mfma_f32_16x16x32_bf16(wf[i*6+k], bo[nt], eo[i][nt], 0, 0, 0);
    }
    #pragma unroll
    for (int i = 0; i < 2; ++i){
      #pragma unroll
      for (int rr = 0; rr < 4; ++rr){
        int o = (tb2 + i)*16 + lg*4 + rr;
        float bb = Bf[3*CC + o];
        #pragma unroll
        for (int nt = 0; nt < 4; ++nt){
          int tok = nt*16 + lr;
          size_t g = (size_t)(b*CC + o)*65536 + (size_t)(y0 + (tok >> 3))*256 + x0 + (tok & 7);
          out[g] = eo[i][nt][rr] + bb + q2d[g];
        }
      }
    }
  }
}

extern "C" void kernel_launch(void* const* d_in, const int* in_sizes, int n_in,
                              void* d_out, int out_size, void* d_ws, size_t ws_size,
                              hipStream_t stream)
{
  const float* q2d    = (const float*)d_in[0];
  const float* kv2d   = (const float*)d_in[1];
  const float* wq     = (const float*)d_in[2];
  const float* bq     = (const float*)d_in[3];
  const float* wk     = (const float*)d_in[4];
  const float* bk     = (const float*)d_in[5];
  const float* wv     = (const float*)d_in[6];
  const float* bv     = (const float*)d_in[7];
  const float* in_w   = (const float*)d_in[8];
  const float* in_b   = (const float*)d_in[9];
  const float* out_w  = (const float*)d_in[10];
  const float* out_b  = (const float*)d_in[11];
  const float* proj_w = (const float*)d_in[12];
  const float* proj_b = (const float*)d_in[13];

  unsigned short* Wf = (unsigned short*)d_ws;
  float* Bf = (float*)((char*)d_ws + WFRAG_USHORTS*2);
  float* out = (float*)d_out;

  fuse_weights<<<4*CC, CC, 0, stream>>>(wq,bq,wk,bk,wv,bv,in_w,in_b,
                                        out_w,out_b,proj_w,proj_b, Wf, Bf);
  win_attn<<<4096, 384, 0, stream>>>(q2d, kv2d, Wf, Bf, out);
}

// Round 13
// 357.194 us; speedup vs baseline: 1.2337x; 1.0175x over previous
//
#include <hip/hip_runtime.h>

#define CC 192
#define WFRAG_USHORTS (4*6*12*512)
#define SX 202   // [tok][ch] stride (ushorts): 404B = 101 dwords == 5 mod 32

typedef __attribute__((ext_vector_type(8))) short bf16x8;
typedef __attribute__((ext_vector_type(4))) float f32x4;

__device__ __forceinline__ unsigned short f2b(float f){
  unsigned u = __float_as_uint(f);
  return (unsigned short)((u + 0x7fffu + ((u >> 16) & 1u)) >> 16);
}
__device__ __forceinline__ unsigned pk2(float a, float b){
  return (unsigned)f2b(a) | ((unsigned)f2b(b) << 16);
}

// Weights packed in MFMA-fragment order: Wf[mat][k][n][lane][8]; one wave
// B/A-fragment = one contiguous 1KB block. 1/sqrt(32) folded into Q mat+bias.
__global__ void fuse_weights(const float* __restrict__ wq, const float* __restrict__ bq,
                             const float* __restrict__ wk, const float* __restrict__ bk,
                             const float* __restrict__ wv, const float* __restrict__ bv,
                             const float* __restrict__ in_w, const float* __restrict__ in_b,
                             const float* __restrict__ out_w, const float* __restrict__ out_b,
                             const float* __restrict__ proj_w, const float* __restrict__ proj_b,
                             unsigned short* __restrict__ Wf, float* __restrict__ Bf)
{
  int mat = blockIdx.x / CC, o = blockIdx.x % CC, ci = threadIdx.x;
  const float *A, *Bm, *bs, *ba; int aoff, boff; float scale = 1.f;
  if (mat == 0){ A=in_w; aoff=0;    Bm=wq;    bs=bq;    ba=in_b;   boff=0;    scale=0.17677669529663687f; }
  else if (mat==1){ A=in_w; aoff=CC;   Bm=wk;    bs=bk;    ba=in_b;   boff=CC;   }
  else if (mat==2){ A=in_w; aoff=2*CC; Bm=wv;    bs=bv;    ba=in_b;   boff=2*CC; }
  else            { A=proj_w; aoff=0;  Bm=out_w; bs=out_b; ba=proj_b; boff=0;    }
  const float* ar = A + (size_t)(aoff + o) * CC;
  float acc = 0.f;
  for (int m = 0; m < CC; ++m) acc = fmaf(ar[m], Bm[m*CC + ci], acc);
  int k = ci >> 5, n = o >> 4, lgv = (ci >> 3) & 3, e = ci & 7;
  int lane = (o & 15) | (lgv << 4);
  Wf[(((mat*6 + k)*12 + n) << 9) + lane*8 + e] = f2b(acc * scale);
  if (ci == 0){
    float bacc = 0.f;
    for (int m = 0; m < CC; ++m) bacc = fmaf(ar[m], bs[m], bacc);
    Bf[mat*CC + o] = (bacc + ba[boff + o]) * scale;
  }
}

__global__ __launch_bounds__(384, 4) void win_attn(
    const float* __restrict__ q2d, const float* __restrict__ kv2d,
    const unsigned short* __restrict__ Wf, const float* __restrict__ Bf,
    float* __restrict__ out)
{
  __shared__ unsigned short QK[2][64*SX]; // [0]: Xq -> Q -> O ; [1]: Xkv -> K

  const int t = threadIdx.x;
  const int w = t >> 6, lane = t & 63, lr = lane & 15, lg = lane >> 4;
  const int bid = blockIdx.x;
  const int wid = (bid & 7) * 512 + (bid >> 3);   // XCD-chunked, bijective
  const int b = wid >> 10, l = wid & 1023;
  const int y0 = (l >> 5) << 3, x0 = (l & 31) << 3;
  const float* qsrc  = q2d  + (size_t)b * CC * 65536;
  const float* kvsrc = kv2d + (size_t)b * CC * 65536;
  const int tb2 = 2 * w;     // wave's 2 16-ch tiles == head w's 32 channels

  auto stage = [&](const float* __restrict__ src, unsigned short* __restrict__ dst){
    #pragma unroll
    for (int i = 0; i < 4; ++i){
      int lin = i*384 + t;
      int c2 = lin >> 4, tok0 = (lin & 15) << 2;
      int gy = (y0 + (tok0 >> 3)) * 256 + x0 + (tok0 & 7);
      float4 va = *(const float4*)&src[(size_t)(2*c2)   * 65536 + gy];
      float4 vb = *(const float4*)&src[(size_t)(2*c2+1) * 65536 + gy];
      float fa[4] = {va.x, va.y, va.z, va.w};
      float fb[4] = {vb.x, vb.y, vb.z, vb.w};
      #pragma unroll
      for (int jj = 0; jj < 4; ++jj)
        *(unsigned*)&dst[(tok0 + jj)*SX + 2*c2] = pk2(fa[jj], fb[jj]);
    }
  };

  stage(qsrc,  QK[0]);
  stage(kvsrc, QK[1]);
  __syncthreads();                                    // B1

  // ---- A1: V projection (head w's 32 chs) in two 6-frag halves ----
  bf16x8 vp[2][2];
  {
    // half i=0
    bf16x8 wv[6];
    #pragma unroll
    for (int k = 0; k < 6; ++k)
      wv[k] = *(const bf16x8*)&Wf[(((12 + k)*12 + tb2) << 9) + lane*8];
    __builtin_amdgcn_sched_barrier(0);
    f32x4 va[4] = {};
    #pragma unroll
    for (int k = 0; k < 6; ++k){
      #pragma unroll
      for (int m = 0; m < 4; ++m){
        bf16x8 a = *(const bf16x8*)&QK[1][(m*16 + lr)*SX + k*32 + lg*8];
        va[m] = __builtin_amdgcn_mfma_f32_16x16x32_bf16(a, wv[k], va[m], 0, 0, 0);
      }
    }
    {
      float bb = Bf[2*CC + tb2*16 + lr];
      #pragma unroll
      for (int kt = 0; kt < 2; ++kt){
        bf16x8 v;
        ((unsigned*)&v)[0] = pk2(va[2*kt][0] + bb,   va[2*kt][1] + bb);
        ((unsigned*)&v)[1] = pk2(va[2*kt][2] + bb,   va[2*kt][3] + bb);
        ((unsigned*)&v)[2] = pk2(va[2*kt+1][0] + bb, va[2*kt+1][1] + bb);
        ((unsigned*)&v)[3] = pk2(va[2*kt+1][2] + bb, va[2*kt+1][3] + bb);
        vp[0][kt] = v;
      }
    }
    // half i=1
    #pragma unroll
    for (int k = 0; k < 6; ++k)
      wv[k] = *(const bf16x8*)&Wf[(((12 + k)*12 + tb2 + 1) << 9) + lane*8];
    __builtin_amdgcn_sched_barrier(0);
    f32x4 vc[4] = {};
    #pragma unroll
    for (int k = 0; k < 6; ++k){
      #pragma unroll
      for (int m = 0; m < 4; ++m){
        bf16x8 a = *(const bf16x8*)&QK[1][(m*16 + lr)*SX + k*32 + lg*8];
        vc[m] = __builtin_amdgcn_mfma_f32_16x16x32_bf16(a, wv[k], vc[m], 0, 0, 0);
      }
    }
    {
      float bb = Bf[2*CC + (tb2 + 1)*16 + lr];
      #pragma unroll
      for (int kt = 0; kt < 2; ++kt){
        bf16x8 v;
        ((unsigned*)&v)[0] = pk2(vc[2*kt][0] + bb,   vc[2*kt][1] + bb);
        ((unsigned*)&v)[1] = pk2(vc[2*kt][2] + bb,   vc[2*kt][3] + bb);
        ((unsigned*)&v)[2] = pk2(vc[2*kt+1][0] + bb, vc[2*kt+1][1] + bb);
        ((unsigned*)&v)[3] = pk2(vc[2*kt+1][2] + bb, vc[2*kt+1][3] + bb);
        vp[1][kt] = v;
      }
    }
  }

  // ---- A2: Q projection (reads QK[0]=Xq), two halves; both accs to barrier ----
  {
    f32x4 qa0[4] = {}, qa1[4] = {};
    {
      bf16x8 wq_[6];
      #pragma unroll
      for (int k = 0; k < 6; ++k)
        wq_[k] = *(const bf16x8*)&Wf[((k*12 + tb2) << 9) + lane*8];
      __builtin_amdgcn_sched_barrier(0);
      #pragma unroll
      for (int k = 0; k < 6; ++k){
        #pragma unroll
        for (int m = 0; m < 4; ++m){
          bf16x8 a = *(const bf16x8*)&QK[0][(m*16 + lr)*SX + k*32 + lg*8];
          qa0[m] = __builtin_amdgcn_mfma_f32_16x16x32_bf16(a, wq_[k], qa0[m], 0, 0, 0);
        }
      }
      #pragma unroll
      for (int k = 0; k < 6; ++k)
        wq_[k] = *(const bf16x8*)&Wf[((k*12 + tb2 + 1) << 9) + lane*8];
      __builtin_amdgcn_sched_barrier(0);
      #pragma unroll
      for (int k = 0; k < 6; ++k){
        #pragma unroll
        for (int m = 0; m < 4; ++m){
          bf16x8 a = *(const bf16x8*)&QK[0][(m*16 + lr)*SX + k*32 + lg*8];
          qa1[m] = __builtin_amdgcn_mfma_f32_16x16x32_bf16(a, wq_[k], qa1[m], 0, 0, 0);
        }
      }
    }
    __syncthreads();                                  // B2: all Xq reads done
    {
      int ch0 = tb2*16 + lr, ch1 = (tb2 + 1)*16 + lr;
      float b0 = Bf[ch0], b1 = Bf[ch1];
      #pragma unroll
      for (int m = 0; m < 4; ++m)
        #pragma unroll
        for (int rr = 0; rr < 4; ++rr){
          QK[0][(m*16 + lg*4 + rr)*SX + ch0] = f2b(qa0[m][rr] + b0);
          QK[0][(m*16 + lg*4 + rr)*SX + ch1] = f2b(qa1[m][rr] + b1);
        }
    }
  }

  // ---- A3: K projection (reads QK[1]=Xkv), two halves ----
  {
    f32x4 ka0[4] = {}, ka1[4] = {};
    {
      bf16x8 wk_[6];
      #pragma unroll
      for (int k = 0; k < 6; ++k)
        wk_[k] = *(const bf16x8*)&Wf[(((6 + k)*12 + tb2) << 9) + lane*8];
      __builtin_amdgcn_sched_barrier(0);
      #pragma unroll
      for (int k = 0; k < 6; ++k){
        #pragma unroll
        for (int m = 0; m < 4; ++m){
          bf16x8 a = *(const bf16x8*)&QK[1][(m*16 + lr)*SX + k*32 + lg*8];
          ka0[m] = __builtin_amdgcn_mfma_f32_16x16x32_bf16(a, wk_[k], ka0[m], 0, 0, 0);
        }
      }
      #pragma unroll
      for (int k = 0; k < 6; ++k)
        wk_[k] = *(const bf16x8*)&Wf[(((6 + k)*12 + tb2 + 1) << 9) + lane*8];
      __builtin_amdgcn_sched_barrier(0);
      #pragma unroll
      for (int k = 0; k < 6; ++k){
        #pragma unroll
        for (int m = 0; m < 4; ++m){
          bf16x8 a = *(const bf16x8*)&QK[1][(m*16 + lr)*SX + k*32 + lg*8];
          ka1[m] = __builtin_amdgcn_mfma_f32_16x16x32_bf16(a, wk_[k], ka1[m], 0, 0, 0);
        }
      }
    }
    __syncthreads();                                  // B3: all Xkv reads done
    {
      int ch0 = tb2*16 + lr, ch1 = (tb2 + 1)*16 + lr;
      float b0 = Bf[CC + ch0], b1 = Bf[CC + ch1];
      #pragma unroll
      for (int m = 0; m < 4; ++m)
        #pragma unroll
        for (int rr = 0; rr < 4; ++rr){
          QK[1][(m*16 + lg*4 + rr)*SX + ch0] = f2b(ka0[m][rr] + b0);
          QK[1][(m*16 + lg*4 + rr)*SX + ch1] = f2b(ka1[m][rr] + b1);
        }
    }
  }
  __syncthreads();                                    // B4: Q and K visible

  // ---- attention: wave w == head w; V in regs; K frags hoisted ----
  {
    const int h = w;
    bf16x8 ka[4];
    #pragma unroll
    for (int m = 0; m < 4; ++m)
      ka[m] = *(const bf16x8*)&QK[1][(m*16 + lr)*SX + h*32 + lg*8];
    #pragma unroll
    for (int r = 0; r < 4; ++r){
      const int r0 = r << 4;
      f32x4 st[4] = {};
      bf16x8 bq_ = *(const bf16x8*)&QK[0][(r0 + lr)*SX + h*32 + lg*8];
      #pragma unroll
      for (int m = 0; m < 4; ++m)
        st[m] = __builtin_amdgcn_mfma_f32_16x16x32_bf16(ka[m], bq_, st[m], 0, 0, 0);
      float mx = st[0][0];
      #pragma unroll
      for (int m = 0; m < 4; ++m)
        #pragma unroll
        for (int rr = 0; rr < 4; ++rr) mx = fmaxf(mx, st[m][rr]);
      mx = fmaxf(mx, __shfl_xor(mx, 16));
      mx = fmaxf(mx, __shfl_xor(mx, 32));
      float p[16]; float s = 0.f;
      #pragma unroll
      for (int m = 0; m < 4; ++m)
        #pragma unroll
        for (int rr = 0; rr < 4; ++rr){ float e = __expf(st[m][rr] - mx); p[m*4+rr] = e; s += e; }
      s += __shfl_xor(s, 16); s += __shfl_xor(s, 32);
      float inv = 1.f / s;
      #pragma unroll
      for (int i2 = 0; i2 < 16; ++i2) p[i2] *= inv;
      f32x4 o0 = {}, o1 = {};
      #pragma unroll
      for (int kt = 0; kt < 2; ++kt){
        bf16x8 ap;
        ((unsigned*)&ap)[0] = pk2(p[8*kt+0], p[8*kt+1]);
        ((unsigned*)&ap)[1] = pk2(p[8*kt+2], p[8*kt+3]);
        ((unsigned*)&ap)[2] = pk2(p[8*kt+4], p[8*kt+5]);
        ((unsigned*)&ap)[3] = pk2(p[8*kt+6], p[8*kt+7]);
        o0 = __builtin_amdgcn_mfma_f32_16x16x32_bf16(ap, vp[0][kt], o0, 0, 0, 0);
        o1 = __builtin_amdgcn_mfma_f32_16x16x32_bf16(ap, vp[1][kt], o1, 0, 0, 0);
      }
      // O overwrites this head's own Q cells (read bq_ above, sole reader)
      #pragma unroll
      for (int rr = 0; rr < 4; ++rr){
        int tok = r0 + lg*4 + rr;
        QK[0][tok*SX + h*32 + lr]      = f2b(o0[rr]);
        QK[0][tok*SX + h*32 + 16 + lr] = f2b(o1[rr]);
      }
    }
  }
  __syncthreads();                                    // B5: O complete

  // ---- out-proj: E2^T = Wo_f * O^T, two halves with per-half stores ----
  {
    #pragma unroll
    for (int ii = 0; ii < 2; ++ii){
      bf16x8 wo[6];
      #pragma unroll
      for (int k = 0; k < 6; ++k)
        wo[k] = *(const bf16x8*)&Wf[(((18 + k)*12 + tb2 + ii) << 9) + lane*8];
      __builtin_amdgcn_sched_barrier(0);
      f32x4 eo[4] = {};
      #pragma unroll
      for (int k = 0; k < 6; ++k){
        #pragma unroll
        for (int nt = 0; nt < 4; ++nt){
          bf16x8 bo = *(const bf16x8*)&QK[0][(nt*16 + lr)*SX + k*32 + lg*8];
          eo[nt] = __builtin_amdgcn_mfma_f32_16x16x32_bf16(wo[k], bo, eo[nt], 0, 0, 0);
        }
      }
      #pragma unroll
      for (int rr = 0; rr < 4; ++rr){
        int o = (tb2 + ii)*16 + lg*4 + rr;
        float bb = Bf[3*CC + o];
        #pragma unroll
        for (int nt = 0; nt < 4; ++nt){
          int tok = nt*16 + lr;
          size_t g = (size_t)(b*CC + o)*65536 + (size_t)(y0 + (tok >> 3))*256 + x0 + (tok & 7);
          out[g] = eo[nt][rr] + bb + q2d[g];
        }
      }
    }
  }
}

extern "C" void kernel_launch(void* const* d_in, const int* in_sizes, int n_in,
                              void* d_out, int out_size, void* d_ws, size_t ws_size,
                              hipStream_t stream)
{
  const float* q2d    = (const float*)d_in[0];
  const float* kv2d   = (const float*)d_in[1];
  const float* wq     = (const float*)d_in[2];
  const float* bq     = (const float*)d_in[3];
  const float* wk     = (const float*)d_in[4];
  const float* bk     = (const float*)d_in[5];
  const float* wv     = (const float*)d_in[6];
  const float* bv     = (const float*)d_in[7];
  const float* in_w   = (const float*)d_in[8];
  const float* in_b   = (const float*)d_in[9];
  const float* out_w  = (const float*)d_in[10];
  const float* out_b  = (const float*)d_in[11];
  const float* proj_w = (const float*)d_in[12];
  const float* proj_b = (const float*)d_in[13];

  unsigned short* Wf = (unsigned short*)d_ws;
  float* Bf = (float*)((char*)d_ws + WFRAG_USHORTS*2);
  float* out = (float*)d_out;

  fuse_weights<<<4*CC, CC, 0, stream>>>(wq,bq,wk,bk,wv,bv,in_w,in_b,
                                        out_w,out_b,proj_w,proj_b, Wf, Bf);
  win_attn<<<4096, 384, 0, stream>>>(q2d, kv2d, Wf, Bf, out);
}